// Round 1
// baseline (3748.990 us; speedup 1.0000x reference)
//
#include <hip/hip_runtime.h>
#include <math.h>

#define NN   20000
#define NE   200000
#define NG   128
#define EMBD 256
#define NL   4
#define RBFD 10
#define EPB  32   // edges per block in edge kernel

// ---------------- prep kernels ----------------

// xn[n][c] = emb_table[x[n]][c]   (float4 granularity)
__global__ void k_embed(const int* __restrict__ x, const float* __restrict__ emb,
                        float* __restrict__ xn) {
  int idx = blockIdx.x * blockDim.x + threadIdx.x;   // float4 index
  if (idx >= NN * (EMBD / 4)) return;
  int n  = idx >> 6;
  int c4 = (idx & 63) << 2;
  float4 v = *(const float4*)(emb + (size_t)x[n] * EMBD + c4);
  *(float4*)(xn + (size_t)n * EMBD + c4) = v;
}

// rbf[e][k] = exp(-((d - k*w)/w)^2), w = 8/9
__global__ void k_rbf(const float* __restrict__ e, float* __restrict__ rbf) {
  int idx = blockIdx.x * blockDim.x + threadIdx.x;
  if (idx >= NE) return;
  float d = e[idx];
  const float width = 8.0f / 9.0f;
  #pragma unroll
  for (int k = 0; k < RBFD; ++k) {
    float t = (d - (float)k * width) / width;
    rbf[(size_t)idx * RBFD + k] = __expf(-t * t);
  }
}

// weff[l][gf][k][c] = (We @ W*_e[l])[k][c];  beff[l][gf][c] = be @ W*_e[l] + b*[l]
__global__ void k_wsmall(const float* __restrict__ We, const float* __restrict__ be,
                         const float* __restrict__ Wge, const float* __restrict__ bg,
                         const float* __restrict__ Wfe, const float* __restrict__ bf,
                         float* __restrict__ weff, float* __restrict__ beff) {
  int tid = blockIdx.x * blockDim.x + threadIdx.x;
  const int WPER = RBFD * EMBD;   // 2560
  if (tid < NL * 2 * WPER) {
    int l  = tid / (2 * WPER);
    int r  = tid % (2 * WPER);
    int gf = r / WPER;
    int r2 = r % WPER;
    int k = r2 / EMBD, c = r2 % EMBD;
    const float* W = (gf == 0 ? Wge : Wfe) + (size_t)l * EMBD * EMBD;
    float s = 0.f;
    for (int j = 0; j < EMBD; ++j) s += We[k * EMBD + j] * W[(size_t)j * EMBD + c];
    weff[tid] = s;
  } else {
    int t2 = tid - NL * 2 * WPER;
    if (t2 >= NL * 2 * EMBD) return;
    int l  = t2 / (2 * EMBD);
    int r  = t2 % (2 * EMBD);
    int gf = r / EMBD, c = r % EMBD;
    const float* W = (gf == 0 ? Wge : Wfe) + (size_t)l * EMBD * EMBD;
    const float* b = (gf == 0 ? bg : bf) + (size_t)l * EMBD;
    float s = b[c];
    for (int j = 0; j < EMBD; ++j) s += be[j] * W[(size_t)j * EMBD + c];
    beff[t2] = s;
  }
}

// ---------------- per-layer kernels ----------------

// Y(20000 x 1024) = xn @ [Wg_x | Wf_x | Wg_n | Wf_n]   (each 256x256)
// 64x64 tile, BK=32, 256 threads, 4x4 micro-tile
__global__ __launch_bounds__(256) void k_nodemm(
    const float* __restrict__ xn,
    const float* __restrict__ Wgx, const float* __restrict__ Wfx,
    const float* __restrict__ Wgn, const float* __restrict__ Wfn,
    float* __restrict__ Y) {
  __shared__ float As[64][33];
  __shared__ float Bs[32][64];
  const int tid = threadIdx.x;
  const int tx = tid & 15, ty = tid >> 4;
  const int row0 = blockIdx.x << 6;
  const int by = blockIdx.y;              // 0..15
  const int q = by >> 2;                  // quadrant
  const float* W = (q == 0) ? Wgx : (q == 1) ? Wfx : (q == 2) ? Wgn : Wfn;
  const int wc0 = (by & 3) << 6;          // column offset within 256-wide W
  float acc[4][4] = {};
  for (int k0 = 0; k0 < EMBD; k0 += 32) {
    #pragma unroll
    for (int i = 0; i < 8; ++i) {
      int idx = tid + (i << 8);
      int r = idx >> 5, c = idx & 31;
      int gr = row0 + r;
      As[r][c] = (gr < NN) ? xn[(size_t)gr * EMBD + k0 + c] : 0.f;
    }
    #pragma unroll
    for (int i = 0; i < 8; ++i) {
      int idx = tid + (i << 8);
      int r = idx >> 6, c = idx & 63;
      Bs[r][c] = W[(size_t)(k0 + r) * EMBD + wc0 + c];
    }
    __syncthreads();
    #pragma unroll
    for (int k = 0; k < 32; ++k) {
      float a0 = As[(ty << 2) + 0][k];
      float a1 = As[(ty << 2) + 1][k];
      float a2 = As[(ty << 2) + 2][k];
      float a3 = As[(ty << 2) + 3][k];
      float4 b = *(const float4*)&Bs[k][tx << 2];
      acc[0][0] += a0 * b.x; acc[0][1] += a0 * b.y; acc[0][2] += a0 * b.z; acc[0][3] += a0 * b.w;
      acc[1][0] += a1 * b.x; acc[1][1] += a1 * b.y; acc[1][2] += a1 * b.z; acc[1][3] += a1 * b.w;
      acc[2][0] += a2 * b.x; acc[2][1] += a2 * b.y; acc[2][2] += a2 * b.z; acc[2][3] += a2 * b.w;
      acc[3][0] += a3 * b.x; acc[3][1] += a3 * b.y; acc[3][2] += a3 * b.z; acc[3][3] += a3 * b.w;
    }
    __syncthreads();
  }
  #pragma unroll
  for (int i = 0; i < 4; ++i) {
    int gr = row0 + (ty << 2) + i;
    if (gr < NN) {
      float4 v = make_float4(acc[i][0], acc[i][1], acc[i][2], acc[i][3]);
      *(float4*)(Y + (size_t)gr * 1024 + (by << 6) + (tx << 2)) = v;
    }
  }
}

__device__ __forceinline__ float sigmoidf_(float z) {
  return 1.0f / (1.0f + __expf(-z));
}
__device__ __forceinline__ float softplusf_(float z) {
  return fmaxf(z, 0.0f) + log1pf(__expf(-fabsf(z)));
}

// per edge: zg = Ax[dst] + An[src] + rbf@Weg + bg_eff ; zf likewise
// msg = sigmoid(zg)*softplus(zf); atomicAdd into agg[dst]
__global__ __launch_bounds__(256) void k_edge(
    const float* __restrict__ Y, const float* __restrict__ rbf,
    const int* __restrict__ src, const int* __restrict__ dst,
    const float* __restrict__ weff, const float* __restrict__ beff,
    float* __restrict__ agg, int layer) {
  __shared__ float WgS[RBFD * EMBD];
  __shared__ float WfS[RBFD * EMBD];
  __shared__ float bS[2 * EMBD];
  const int tid = threadIdx.x;
  const float* wbase = weff + (size_t)layer * 2 * RBFD * EMBD;
  for (int i = tid; i < RBFD * EMBD; i += 256) {
    WgS[i] = wbase[i];
    WfS[i] = wbase[RBFD * EMBD + i];
  }
  for (int i = tid; i < 2 * EMBD; i += 256) bS[i] = beff[(size_t)layer * 2 * EMBD + i];
  __syncthreads();
  const int wave = tid >> 6, lane = tid & 63;
  const int c4 = lane << 2;
  const int e0 = blockIdx.x * EPB;
  const float4 bg4 = *(const float4*)&bS[c4];
  const float4 bf4 = *(const float4*)&bS[EMBD + c4];
  for (int e = e0 + wave; e < e0 + EPB; e += 4) {
    int s = src[e], d = dst[e];
    const float4 Ax = *(const float4*)(Y + (size_t)d * 1024 + c4);
    const float4 Fx = *(const float4*)(Y + (size_t)d * 1024 + 256 + c4);
    const float4 An = *(const float4*)(Y + (size_t)s * 1024 + 512 + c4);
    const float4 Fn = *(const float4*)(Y + (size_t)s * 1024 + 768 + c4);
    float rv = (lane < RBFD) ? rbf[(size_t)e * RBFD + lane] : 0.f;
    float4 zg = make_float4(Ax.x + An.x + bg4.x, Ax.y + An.y + bg4.y,
                            Ax.z + An.z + bg4.z, Ax.w + An.w + bg4.w);
    float4 zf = make_float4(Fx.x + Fn.x + bf4.x, Fx.y + Fn.y + bf4.y,
                            Fx.z + Fn.z + bf4.z, Fx.w + Fn.w + bf4.w);
    #pragma unroll
    for (int k = 0; k < RBFD; ++k) {
      float rk = __shfl(rv, k, 64);
      float4 wg = *(const float4*)&WgS[k * EMBD + c4];
      float4 wf = *(const float4*)&WfS[k * EMBD + c4];
      zg.x += rk * wg.x; zg.y += rk * wg.y; zg.z += rk * wg.z; zg.w += rk * wg.w;
      zf.x += rk * wf.x; zf.y += rk * wf.y; zf.z += rk * wf.z; zf.w += rk * wf.w;
    }
    float m0 = sigmoidf_(zg.x) * softplusf_(zf.x);
    float m1 = sigmoidf_(zg.y) * softplusf_(zf.y);
    float m2 = sigmoidf_(zg.z) * softplusf_(zf.z);
    float m3 = sigmoidf_(zg.w) * softplusf_(zf.w);
    float* ap = agg + (size_t)d * EMBD + c4;
    atomicAdd(ap + 0, m0);
    atomicAdd(ap + 1, m1);
    atomicAdd(ap + 2, m2);
    atomicAdd(ap + 3, m3);
  }
}

// xn += agg; agg = 0   (float4 granularity)
__global__ void k_update(float* __restrict__ xn, float* __restrict__ agg) {
  int idx = blockIdx.x * blockDim.x + threadIdx.x;
  if (idx >= NN * (EMBD / 4)) return;
  float4* x4 = (float4*)xn;
  float4* a4 = (float4*)agg;
  float4 a = a4[idx];
  float4 v = x4[idx];
  v.x += a.x; v.y += a.y; v.z += a.z; v.w += a.w;
  x4[idx] = v;
  a4[idx] = make_float4(0.f, 0.f, 0.f, 0.f);
}

// ---------------- readout ----------------

// per node: xs = xn@Wn; atomicAdd into per-graph sums + counts
__global__ __launch_bounds__(256) void k_readout(
    const float* __restrict__ xn, const float* __restrict__ Wn,
    const int* __restrict__ gidx, float* __restrict__ gsum, float* __restrict__ gcnt) {
  __shared__ float WnT[12 * EMBD];  // transposed: [c][k]
  const int tid = threadIdx.x;
  for (int i = tid; i < 12 * EMBD; i += 256) {
    int c = i >> 8, k = i & 255;
    WnT[i] = Wn[k * 12 + c];
  }
  __syncthreads();
  const int wave = tid >> 6, lane = tid & 63;
  const int n = blockIdx.x * 4 + wave;
  if (n >= NN) return;
  float4 xv = *(const float4*)(xn + (size_t)n * EMBD + (lane << 2));
  float acc[12];
  #pragma unroll
  for (int c = 0; c < 12; ++c) {
    const float4 w = *(const float4*)&WnT[c * EMBD + (lane << 2)];
    acc[c] = xv.x * w.x + xv.y * w.y + xv.z * w.z + xv.w * w.w;
  }
  #pragma unroll
  for (int c = 0; c < 12; ++c) {
    float v = acc[c];
    #pragma unroll
    for (int off = 32; off; off >>= 1) v += __shfl_down(v, off, 64);
    acc[c] = v;
  }
  if (lane == 0) {
    int g = gidx[n];
    #pragma unroll
    for (int c = 0; c < 12; ++c) atomicAdd(&gsum[g * 12 + c], acc[c]);
    atomicAdd(&gcnt[g], 1.0f);
  }
}

__global__ void k_final(const float* __restrict__ gsum, const float* __restrict__ gcnt,
                        const float* __restrict__ bn, float* __restrict__ out) {
  int idx = blockIdx.x * blockDim.x + threadIdx.x;
  if (idx >= NG * 12) return;
  int g = idx / 12, c = idx % 12;
  out[idx] = gsum[idx] / fmaxf(gcnt[g], 1.0f) + bn[c];
}

// ---------------- launch ----------------

extern "C" void kernel_launch(void* const* d_in, const int* in_sizes, int n_in,
                              void* d_out, int out_size, void* d_ws, size_t ws_size,
                              hipStream_t stream) {
  const int*   x   = (const int*)d_in[0];
  const int*   src = (const int*)d_in[1];
  const int*   dst = (const int*)d_in[2];
  const float* e   = (const float*)d_in[3];
  const int*   gi  = (const int*)d_in[4];
  const float* emb = (const float*)d_in[5];
  const float* We  = (const float*)d_in[6];
  const float* be  = (const float*)d_in[7];
  const float* Wgx = (const float*)d_in[8];
  const float* Wgn = (const float*)d_in[9];
  const float* Wge = (const float*)d_in[10];
  const float* bg  = (const float*)d_in[11];
  const float* Wfx = (const float*)d_in[12];
  const float* Wfn = (const float*)d_in[13];
  const float* Wfe = (const float*)d_in[14];
  const float* bf  = (const float*)d_in[15];
  const float* Wn  = (const float*)d_in[16];
  const float* bn  = (const float*)d_in[17];
  float* out = (float*)d_out;

  char* ws = (char*)d_ws;
  size_t off = 0;
  auto alloc = [&](size_t bytes) {
    void* p = ws + off;
    off += (bytes + 255) & ~(size_t)255;
    return p;
  };
  float* xn   = (float*)alloc((size_t)NN * EMBD * 4);
  float* agg  = (float*)alloc((size_t)NN * EMBD * 4);
  float* Y    = (float*)alloc((size_t)NN * 1024 * 4);
  float* rbf  = (float*)alloc((size_t)NE * RBFD * 4);
  float* weff = (float*)alloc((size_t)NL * 2 * RBFD * EMBD * 4);
  float* beff = (float*)alloc((size_t)NL * 2 * EMBD * 4);
  float* gsum = (float*)alloc((size_t)NG * 12 * 4);
  float* gcnt = (float*)alloc((size_t)NG * 4);
  (void)ws_size; (void)in_sizes; (void)n_in; (void)out_size;

  hipMemsetAsync(agg, 0, (size_t)NN * EMBD * 4, stream);
  hipMemsetAsync(gsum, 0, (size_t)NG * 12 * 4, stream);
  hipMemsetAsync(gcnt, 0, (size_t)NG * 4, stream);

  k_embed<<<(NN * (EMBD / 4) + 255) / 256, 256, 0, stream>>>(x, emb, xn);
  k_rbf<<<(NE + 255) / 256, 256, 0, stream>>>(e, rbf);
  k_wsmall<<<(NL * 2 * (RBFD + 1) * EMBD + 255) / 256, 256, 0, stream>>>(
      We, be, Wge, bg, Wfe, bf, weff, beff);

  dim3 mmgrid((NN + 63) / 64, 16);
  for (int l = 0; l < NL; ++l) {
    k_nodemm<<<mmgrid, 256, 0, stream>>>(
        xn, Wgx + (size_t)l * 65536, Wfx + (size_t)l * 65536,
        Wgn + (size_t)l * 65536, Wfn + (size_t)l * 65536, Y);
    k_edge<<<NE / EPB, 256, 0, stream>>>(Y, rbf, src, dst, weff, beff, agg, l);
    k_update<<<(NN * (EMBD / 4) + 255) / 256, 256, 0, stream>>>(xn, agg);
  }
  k_readout<<<NN / 4, 256, 0, stream>>>(xn, Wn, gi, gsum, gcnt);
  k_final<<<(NG * 12 + 255) / 256, 256, 0, stream>>>(gsum, gcnt, bn, out);
}

// Round 2
// 1969.548 us; speedup vs baseline: 1.9035x; 1.9035x over previous
//
#include <hip/hip_runtime.h>
#include <math.h>

#define NN   20000
#define NE   200000
#define NG   128
#define EMBD 256
#define NL   4
#define RBFD 10

// ---------------- prep kernels ----------------

// xn[n][c] = emb_table[x[n]][c]   (float4 granularity)
__global__ void k_embed(const int* __restrict__ x, const float* __restrict__ emb,
                        float* __restrict__ xn) {
  int idx = blockIdx.x * blockDim.x + threadIdx.x;   // float4 index
  if (idx >= NN * (EMBD / 4)) return;
  int n  = idx >> 6;
  int c4 = (idx & 63) << 2;
  float4 v = *(const float4*)(emb + (size_t)x[n] * EMBD + c4);
  *(float4*)(xn + (size_t)n * EMBD + c4) = v;
}

// weff[l][gf][k][c] = (We @ W*_e[l])[k][c];  beff[l][gf][c] = be @ W*_e[l] + b*[l]
__global__ void k_wsmall(const float* __restrict__ We, const float* __restrict__ be,
                         const float* __restrict__ Wge, const float* __restrict__ bg,
                         const float* __restrict__ Wfe, const float* __restrict__ bf,
                         float* __restrict__ weff, float* __restrict__ beff) {
  int tid = blockIdx.x * blockDim.x + threadIdx.x;
  const int WPER = RBFD * EMBD;   // 2560
  if (tid < NL * 2 * WPER) {
    int l  = tid / (2 * WPER);
    int r  = tid % (2 * WPER);
    int gf = r / WPER;
    int r2 = r % WPER;
    int k = r2 / EMBD, c = r2 % EMBD;
    const float* W = (gf == 0 ? Wge : Wfe) + (size_t)l * EMBD * EMBD;
    float s = 0.f;
    for (int j = 0; j < EMBD; ++j) s += We[k * EMBD + j] * W[(size_t)j * EMBD + c];
    weff[tid] = s;
  } else {
    int t2 = tid - NL * 2 * WPER;
    if (t2 >= NL * 2 * EMBD) return;
    int l  = t2 / (2 * EMBD);
    int r  = t2 % (2 * EMBD);
    int gf = r / EMBD, c = r % EMBD;
    const float* W = (gf == 0 ? Wge : Wfe) + (size_t)l * EMBD * EMBD;
    const float* b = (gf == 0 ? bg : bf) + (size_t)l * EMBD;
    float s = b[c];
    for (int j = 0; j < EMBD; ++j) s += be[j] * W[(size_t)j * EMBD + c];
    beff[t2] = s;
  }
}

// ---------------- CSR build ----------------

__global__ void k_hist(const int* __restrict__ dst, int* __restrict__ cnt) {
  int e = blockIdx.x * blockDim.x + threadIdx.x;
  if (e >= NE) return;
  atomicAdd(&cnt[dst[e]], 1);
}

// single-block exclusive scan of 20000 counts -> roff[NN+1], cursor copy
__global__ __launch_bounds__(1024) void k_scan(const int* __restrict__ cnt,
                                               int* __restrict__ roff,
                                               int* __restrict__ cursor) {
  __shared__ int part[1024];
  const int t = threadIdx.x;
  const int CH = 20;  // 1024*20 >= 20000
  int base = t * CH;
  int loc[CH];
  int s = 0;
  #pragma unroll
  for (int i = 0; i < CH; ++i) {
    int idx = base + i;
    int v = (idx < NN) ? cnt[idx] : 0;
    loc[i] = s;
    s += v;
  }
  part[t] = s;
  __syncthreads();
  for (int off = 1; off < 1024; off <<= 1) {
    int v = (t >= off) ? part[t - off] : 0;
    __syncthreads();
    part[t] += v;
    __syncthreads();
  }
  int chunkbase = (t == 0) ? 0 : part[t - 1];
  #pragma unroll
  for (int i = 0; i < CH; ++i) {
    int idx = base + i;
    if (idx < NN) {
      int v = chunkbase + loc[i];
      roff[idx] = v;
      cursor[idx] = v;
    }
  }
  if (t == 1023) roff[NN] = part[1023];
}

// scatter edges into dst-sorted order; compute rbf inline
__global__ void k_scatter(const int* __restrict__ src, const int* __restrict__ dst,
                          const float* __restrict__ edist,
                          int* __restrict__ cursor,
                          int* __restrict__ src_s, float* __restrict__ rbf_s) {
  int e = blockIdx.x * blockDim.x + threadIdx.x;
  if (e >= NE) return;
  int d = dst[e];
  int p = atomicAdd(&cursor[d], 1);
  src_s[p] = src[e];
  float dd = edist[e];
  const float width = 8.0f / 9.0f;
  #pragma unroll
  for (int k = 0; k < RBFD; ++k) {
    float t = (dd - (float)k * width) / width;
    rbf_s[(size_t)p * RBFD + k] = __expf(-t * t);
  }
}

// ---------------- per-layer kernels ----------------

// Y(20000 x 1024) = xn @ [Wg_x | Wf_x | Wg_n | Wf_n]   (each 256x256)
__global__ __launch_bounds__(256) void k_nodemm(
    const float* __restrict__ xn,
    const float* __restrict__ Wgx, const float* __restrict__ Wfx,
    const float* __restrict__ Wgn, const float* __restrict__ Wfn,
    float* __restrict__ Y) {
  __shared__ float As[64][33];
  __shared__ float Bs[32][64];
  const int tid = threadIdx.x;
  const int tx = tid & 15, ty = tid >> 4;
  const int row0 = blockIdx.x << 6;
  const int by = blockIdx.y;              // 0..15
  const int q = by >> 2;                  // quadrant
  const float* W = (q == 0) ? Wgx : (q == 1) ? Wfx : (q == 2) ? Wgn : Wfn;
  const int wc0 = (by & 3) << 6;
  float acc[4][4] = {};
  for (int k0 = 0; k0 < EMBD; k0 += 32) {
    #pragma unroll
    for (int i = 0; i < 8; ++i) {
      int idx = tid + (i << 8);
      int r = idx >> 5, c = idx & 31;
      int gr = row0 + r;
      As[r][c] = (gr < NN) ? xn[(size_t)gr * EMBD + k0 + c] : 0.f;
    }
    #pragma unroll
    for (int i = 0; i < 8; ++i) {
      int idx = tid + (i << 8);
      int r = idx >> 6, c = idx & 63;
      Bs[r][c] = W[(size_t)(k0 + r) * EMBD + wc0 + c];
    }
    __syncthreads();
    #pragma unroll
    for (int k = 0; k < 32; ++k) {
      float a0 = As[(ty << 2) + 0][k];
      float a1 = As[(ty << 2) + 1][k];
      float a2 = As[(ty << 2) + 2][k];
      float a3 = As[(ty << 2) + 3][k];
      float4 b = *(const float4*)&Bs[k][tx << 2];
      acc[0][0] += a0 * b.x; acc[0][1] += a0 * b.y; acc[0][2] += a0 * b.z; acc[0][3] += a0 * b.w;
      acc[1][0] += a1 * b.x; acc[1][1] += a1 * b.y; acc[1][2] += a1 * b.z; acc[1][3] += a1 * b.w;
      acc[2][0] += a2 * b.x; acc[2][1] += a2 * b.y; acc[2][2] += a2 * b.z; acc[2][3] += a2 * b.w;
      acc[3][0] += a3 * b.x; acc[3][1] += a3 * b.y; acc[3][2] += a3 * b.z; acc[3][3] += a3 * b.w;
    }
    __syncthreads();
  }
  #pragma unroll
  for (int i = 0; i < 4; ++i) {
    int gr = row0 + (ty << 2) + i;
    if (gr < NN) {
      float4 v = make_float4(acc[i][0], acc[i][1], acc[i][2], acc[i][3]);
      *(float4*)(Y + (size_t)gr * 1024 + (by << 6) + (tx << 2)) = v;
    }
  }
}

__device__ __forceinline__ float sigmoidf_(float z) {
  return 1.0f / (1.0f + __expf(-z));
}
__device__ __forceinline__ float softplusf_(float z) {
  return fmaxf(z, 0.0f) + log1pf(__expf(-fabsf(z)));
}

// one wave per dst node: accumulate messages over its CSR edge range, xn += sum
__global__ __launch_bounds__(256) void k_agg(
    const float* __restrict__ Y, const int* __restrict__ roff,
    const int* __restrict__ src_s, const float* __restrict__ rbf_s,
    const float* __restrict__ weff, const float* __restrict__ beff,
    float* __restrict__ xn, int layer) {
  __shared__ float WgS[RBFD * EMBD];
  __shared__ float WfS[RBFD * EMBD];
  __shared__ float bS[2 * EMBD];
  const int tid = threadIdx.x;
  const float* wbase = weff + (size_t)layer * 2 * RBFD * EMBD;
  for (int i = tid; i < RBFD * EMBD; i += 256) {
    WgS[i] = wbase[i];
    WfS[i] = wbase[RBFD * EMBD + i];
  }
  for (int i = tid; i < 2 * EMBD; i += 256) bS[i] = beff[(size_t)layer * 2 * EMBD + i];
  __syncthreads();
  const int wave = tid >> 6, lane = tid & 63;
  const int c4 = lane << 2;
  const int n = blockIdx.x * 4 + wave;
  if (n >= NN) return;
  const int j0 = roff[n], j1 = roff[n + 1];
  const int deg = j1 - j0;

  const float4 bg4 = *(const float4*)&bS[c4];
  const float4 bf4 = *(const float4*)&bS[EMBD + c4];
  const float4 Ax = *(const float4*)(Y + (size_t)n * 1024 + c4);
  const float4 Fx = *(const float4*)(Y + (size_t)n * 1024 + 256 + c4);
  const float4 baseg = make_float4(Ax.x + bg4.x, Ax.y + bg4.y, Ax.z + bg4.z, Ax.w + bg4.w);
  const float4 basef = make_float4(Fx.x + bf4.x, Fx.y + bf4.y, Fx.z + bf4.z, Fx.w + bf4.w);

  // preload up to 64 src ids for this node (coalesced), broadcast via shfl
  int sload = (lane < deg) ? src_s[j0 + lane] : 0;

  float4 macc = make_float4(0.f, 0.f, 0.f, 0.f);
  for (int i = 0; i < deg; ++i) {
    int s = (i < 64) ? __shfl(sload, i, 64) : src_s[j0 + i];
    const float4 An = *(const float4*)(Y + (size_t)s * 1024 + 512 + c4);
    const float4 Fn = *(const float4*)(Y + (size_t)s * 1024 + 768 + c4);
    float rv = (lane < RBFD) ? rbf_s[(size_t)(j0 + i) * RBFD + lane] : 0.f;
    float4 zg = make_float4(baseg.x + An.x, baseg.y + An.y, baseg.z + An.z, baseg.w + An.w);
    float4 zf = make_float4(basef.x + Fn.x, basef.y + Fn.y, basef.z + Fn.z, basef.w + Fn.w);
    #pragma unroll
    for (int k = 0; k < RBFD; ++k) {
      float rk = __shfl(rv, k, 64);
      float4 wg = *(const float4*)&WgS[k * EMBD + c4];
      float4 wf = *(const float4*)&WfS[k * EMBD + c4];
      zg.x += rk * wg.x; zg.y += rk * wg.y; zg.z += rk * wg.z; zg.w += rk * wg.w;
      zf.x += rk * wf.x; zf.y += rk * wf.y; zf.z += rk * wf.z; zf.w += rk * wf.w;
    }
    macc.x += sigmoidf_(zg.x) * softplusf_(zf.x);
    macc.y += sigmoidf_(zg.y) * softplusf_(zf.y);
    macc.z += sigmoidf_(zg.z) * softplusf_(zf.z);
    macc.w += sigmoidf_(zg.w) * softplusf_(zf.w);
  }
  float4 xv = *(const float4*)(xn + (size_t)n * EMBD + c4);
  xv.x += macc.x; xv.y += macc.y; xv.z += macc.z; xv.w += macc.w;
  *(float4*)(xn + (size_t)n * EMBD + c4) = xv;
}

// ---------------- readout ----------------

__global__ __launch_bounds__(256) void k_readout(
    const float* __restrict__ xn, const float* __restrict__ Wn,
    const int* __restrict__ gidx, float* __restrict__ gsum, float* __restrict__ gcnt) {
  __shared__ float WnT[12 * EMBD];  // transposed: [c][k]
  const int tid = threadIdx.x;
  for (int i = tid; i < 12 * EMBD; i += 256) {
    int c = i >> 8, k = i & 255;
    WnT[i] = Wn[k * 12 + c];
  }
  __syncthreads();
  const int wave = tid >> 6, lane = tid & 63;
  const int n = blockIdx.x * 4 + wave;
  if (n >= NN) return;
  float4 xv = *(const float4*)(xn + (size_t)n * EMBD + (lane << 2));
  float acc[12];
  #pragma unroll
  for (int c = 0; c < 12; ++c) {
    const float4 w = *(const float4*)&WnT[c * EMBD + (lane << 2)];
    acc[c] = xv.x * w.x + xv.y * w.y + xv.z * w.z + xv.w * w.w;
  }
  #pragma unroll
  for (int c = 0; c < 12; ++c) {
    float v = acc[c];
    #pragma unroll
    for (int off = 32; off; off >>= 1) v += __shfl_down(v, off, 64);
    acc[c] = v;
  }
  if (lane == 0) {
    int g = gidx[n];
    #pragma unroll
    for (int c = 0; c < 12; ++c) atomicAdd(&gsum[g * 12 + c], acc[c]);
    atomicAdd(&gcnt[g], 1.0f);
  }
}

__global__ void k_final(const float* __restrict__ gsum, const float* __restrict__ gcnt,
                        const float* __restrict__ bn, float* __restrict__ out) {
  int idx = blockIdx.x * blockDim.x + threadIdx.x;
  if (idx >= NG * 12) return;
  int g = idx / 12, c = idx % 12;
  out[idx] = gsum[idx] / fmaxf(gcnt[g], 1.0f) + bn[c];
}

// ---------------- launch ----------------

extern "C" void kernel_launch(void* const* d_in, const int* in_sizes, int n_in,
                              void* d_out, int out_size, void* d_ws, size_t ws_size,
                              hipStream_t stream) {
  const int*   x   = (const int*)d_in[0];
  const int*   src = (const int*)d_in[1];
  const int*   dst = (const int*)d_in[2];
  const float* e   = (const float*)d_in[3];
  const int*   gi  = (const int*)d_in[4];
  const float* emb = (const float*)d_in[5];
  const float* We  = (const float*)d_in[6];
  const float* be  = (const float*)d_in[7];
  const float* Wgx = (const float*)d_in[8];
  const float* Wgn = (const float*)d_in[9];
  const float* Wge = (const float*)d_in[10];
  const float* bg  = (const float*)d_in[11];
  const float* Wfx = (const float*)d_in[12];
  const float* Wfn = (const float*)d_in[13];
  const float* Wfe = (const float*)d_in[14];
  const float* bf  = (const float*)d_in[15];
  const float* Wn  = (const float*)d_in[16];
  const float* bn  = (const float*)d_in[17];
  float* out = (float*)d_out;

  char* ws = (char*)d_ws;
  size_t off = 0;
  auto alloc = [&](size_t bytes) {
    void* p = ws + off;
    off += (bytes + 255) & ~(size_t)255;
    return p;
  };
  float* xn    = (float*)alloc((size_t)NN * EMBD * 4);
  float* Y     = (float*)alloc((size_t)NN * 1024 * 4);
  float* rbf_s = (float*)alloc((size_t)NE * RBFD * 4);
  int*   src_s = (int*)alloc((size_t)NE * 4);
  int*   cnt   = (int*)alloc((size_t)NN * 4);
  int*   roff  = (int*)alloc((size_t)(NN + 1) * 4);
  int*   curs  = (int*)alloc((size_t)NN * 4);
  float* weff  = (float*)alloc((size_t)NL * 2 * RBFD * EMBD * 4);
  float* beff  = (float*)alloc((size_t)NL * 2 * EMBD * 4);
  float* gsum  = (float*)alloc((size_t)NG * 12 * 4);
  float* gcnt  = (float*)alloc((size_t)NG * 4);
  (void)ws_size; (void)in_sizes; (void)n_in; (void)out_size;

  hipMemsetAsync(cnt, 0, (size_t)NN * 4, stream);
  hipMemsetAsync(gsum, 0, (size_t)NG * 12 * 4, stream);
  hipMemsetAsync(gcnt, 0, (size_t)NG * 4, stream);

  k_embed<<<(NN * (EMBD / 4) + 255) / 256, 256, 0, stream>>>(x, emb, xn);
  k_wsmall<<<(NL * 2 * (RBFD + 1) * EMBD + 255) / 256, 256, 0, stream>>>(
      We, be, Wge, bg, Wfe, bf, weff, beff);
  k_hist<<<(NE + 255) / 256, 256, 0, stream>>>(dst, cnt);
  k_scan<<<1, 1024, 0, stream>>>(cnt, roff, curs);
  k_scatter<<<(NE + 255) / 256, 256, 0, stream>>>(src, dst, e, curs, src_s, rbf_s);

  dim3 mmgrid((NN + 63) / 64, 16);
  for (int l = 0; l < NL; ++l) {
    k_nodemm<<<mmgrid, 256, 0, stream>>>(
        xn, Wgx + (size_t)l * 65536, Wfx + (size_t)l * 65536,
        Wgn + (size_t)l * 65536, Wfn + (size_t)l * 65536, Y);
    k_agg<<<(NN + 3) / 4, 256, 0, stream>>>(Y, roff, src_s, rbf_s, weff, beff, xn, l);
  }
  k_readout<<<NN / 4, 256, 0, stream>>>(xn, Wn, gi, gsum, gcnt);
  k_final<<<(NG * 12 + 255) / 256, 256, 0, stream>>>(gsum, gcnt, bn, out);
}

// Round 3
// 737.928 us; speedup vs baseline: 5.0804x; 2.6690x over previous
//
#include <hip/hip_runtime.h>
#include <hip/hip_bf16.h>
#include <math.h>

#define NN   20000
#define NE   200000
#define NG   128
#define EMBD 256
#define NL   4
#define RBFD 10

typedef __attribute__((ext_vector_type(8))) short bf16x8;
typedef __attribute__((ext_vector_type(4))) float f32x4;

// ---------------- prep kernels ----------------

// xn[n][c] = emb_table[x[n]][c]; also bf16 copy
__global__ void k_embed(const int* __restrict__ x, const float* __restrict__ emb,
                        float* __restrict__ xn, __hip_bfloat16* __restrict__ xnb) {
  int idx = blockIdx.x * blockDim.x + threadIdx.x;   // float4 index
  if (idx >= NN * (EMBD / 4)) return;
  int n  = idx >> 6;
  int c4 = (idx & 63) << 2;
  float4 v = *(const float4*)(emb + (size_t)x[n] * EMBD + c4);
  *(float4*)(xn + (size_t)n * EMBD + c4) = v;
  __hip_bfloat16* xb = xnb + (size_t)n * EMBD + c4;
  xb[0] = __float2bfloat16(v.x); xb[1] = __float2bfloat16(v.y);
  xb[2] = __float2bfloat16(v.z); xb[3] = __float2bfloat16(v.w);
}

// weff[l][gf][k][c] = (We @ W*_e[l])[k][c];  beff[l][gf][c] = be @ W*_e[l] + b*[l]
__global__ void k_wsmall(const float* __restrict__ We, const float* __restrict__ be,
                         const float* __restrict__ Wge, const float* __restrict__ bg,
                         const float* __restrict__ Wfe, const float* __restrict__ bf,
                         float* __restrict__ weff, float* __restrict__ beff) {
  int tid = blockIdx.x * blockDim.x + threadIdx.x;
  const int WPER = RBFD * EMBD;   // 2560
  if (tid < NL * 2 * WPER) {
    int l  = tid / (2 * WPER);
    int r  = tid % (2 * WPER);
    int gf = r / WPER;
    int r2 = r % WPER;
    int k = r2 / EMBD, c = r2 % EMBD;
    const float* W = (gf == 0 ? Wge : Wfe) + (size_t)l * EMBD * EMBD;
    float s = 0.f;
    for (int j = 0; j < EMBD; ++j) s += We[k * EMBD + j] * W[(size_t)j * EMBD + c];
    weff[tid] = s;
  } else {
    int t2 = tid - NL * 2 * WPER;
    if (t2 >= NL * 2 * EMBD) return;
    int l  = t2 / (2 * EMBD);
    int r  = t2 % (2 * EMBD);
    int gf = r / EMBD, c = r % EMBD;
    const float* W = (gf == 0 ? Wge : Wfe) + (size_t)l * EMBD * EMBD;
    const float* b = (gf == 0 ? bg : bf) + (size_t)l * EMBD;
    float s = b[c];
    for (int j = 0; j < EMBD; ++j) s += be[j] * W[(size_t)j * EMBD + c];
    beff[t2] = s;
  }
}

// WT[l][q][c][k] = W_q[l][k][c] as bf16 (transposed, K-contiguous)
__global__ __launch_bounds__(256) void k_wprep(
    const float* __restrict__ Wgx, const float* __restrict__ Wfx,
    const float* __restrict__ Wgn, const float* __restrict__ Wfn,
    __hip_bfloat16* __restrict__ WT) {
  __shared__ float T[64][65];
  int lq = blockIdx.x; int l = lq >> 2, q = lq & 3;
  const float* W = (q == 0 ? Wgx : q == 1 ? Wfx : q == 2 ? Wgn : Wfn) + (size_t)l * 65536;
  int t = blockIdx.y;
  int k0 = (t & 3) * 64, c0 = (t >> 2) * 64;
  #pragma unroll
  for (int i = 0; i < 16; ++i) {
    int idx = threadIdx.x + i * 256;
    int r = idx >> 6, c = idx & 63;
    T[r][c] = W[(size_t)(k0 + r) * 256 + c0 + c];
  }
  __syncthreads();
  __hip_bfloat16* out = WT + ((size_t)lq * 256) * 256;
  #pragma unroll
  for (int i = 0; i < 16; ++i) {
    int idx = threadIdx.x + i * 256;
    int r = idx >> 6, c = idx & 63;   // output row c0+r (a column of W), col k0+c
    out[(size_t)(c0 + r) * 256 + k0 + c] = __float2bfloat16(T[c][r]);
  }
}

// ---------------- CSR build ----------------

__global__ void k_hist(const int* __restrict__ dst, int* __restrict__ cnt) {
  int e = blockIdx.x * blockDim.x + threadIdx.x;
  if (e >= NE) return;
  atomicAdd(&cnt[dst[e]], 1);
}

__global__ __launch_bounds__(1024) void k_scan(const int* __restrict__ cnt,
                                               int* __restrict__ roff,
                                               int* __restrict__ cursor) {
  __shared__ int part[1024];
  const int t = threadIdx.x;
  const int CH = 20;
  int base = t * CH;
  int loc[CH];
  int s = 0;
  #pragma unroll
  for (int i = 0; i < CH; ++i) {
    int idx = base + i;
    int v = (idx < NN) ? cnt[idx] : 0;
    loc[i] = s;
    s += v;
  }
  part[t] = s;
  __syncthreads();
  for (int off = 1; off < 1024; off <<= 1) {
    int v = (t >= off) ? part[t - off] : 0;
    __syncthreads();
    part[t] += v;
    __syncthreads();
  }
  int chunkbase = (t == 0) ? 0 : part[t - 1];
  #pragma unroll
  for (int i = 0; i < CH; ++i) {
    int idx = base + i;
    if (idx < NN) {
      int v = chunkbase + loc[i];
      roff[idx] = v;
      cursor[idx] = v;
    }
  }
  if (t == 1023) roff[NN] = part[1023];
}

__global__ void k_scatter(const int* __restrict__ src, const int* __restrict__ dst,
                          const float* __restrict__ edist,
                          int* __restrict__ cursor,
                          int* __restrict__ src_s, float* __restrict__ rbf_s) {
  int e = blockIdx.x * blockDim.x + threadIdx.x;
  if (e >= NE) return;
  int d = dst[e];
  int p = atomicAdd(&cursor[d], 1);
  src_s[p] = src[e];
  float dd = edist[e];
  const float width = 8.0f / 9.0f;
  #pragma unroll
  for (int k = 0; k < RBFD; ++k) {
    float t = (dd - (float)k * width) / width;
    rbf_s[(size_t)p * RBFD + k] = __expf(-t * t);
  }
}

// ---------------- per-layer kernels ----------------

// Y(20000 x 1024) = xnb @ [Wg_x | Wf_x | Wg_n | Wf_n]  (bf16 MFMA)
// 128x128 tile, BK=32, 4 waves of 64x64, chunk-XOR-swizzled LDS
__global__ __launch_bounds__(256) void k_nodemm(
    const __hip_bfloat16* __restrict__ xnb, const __hip_bfloat16* __restrict__ WTl,
    float* __restrict__ Y) {
  __shared__ unsigned short As[128 * 32];
  __shared__ unsigned short Bs[128 * 32];
  const int tid = threadIdx.x;
  const int lane = tid & 63;
  const int wave = tid >> 6;
  const int row0 = blockIdx.x << 7;
  const int col0 = blockIdx.y << 7;
  const int q = col0 >> 8;
  const int cb = col0 & 255;
  const unsigned short* xb = (const unsigned short*)xnb;
  const unsigned short* Wb = (const unsigned short*)WTl + ((size_t)q * 256 + cb) * 256;
  const int wr = (wave >> 1) << 6;
  const int wc = (wave & 1) << 6;
  f32x4 acc[4][4] = {};

  for (int k0 = 0; k0 < 256; k0 += 32) {
    #pragma unroll
    for (int h = 0; h < 2; ++h) {
      int c = tid + (h << 8);
      int r = c >> 2, s = c & 3;
      int sw = s ^ ((r >> 1) & 3);
      int ga = row0 + r; if (ga > NN - 1) ga = NN - 1;
      *(bf16x8*)(&As[r * 32 + sw * 8]) =
          *(const bf16x8*)(xb + (size_t)ga * 256 + k0 + s * 8);
      *(bf16x8*)(&Bs[r * 32 + sw * 8]) =
          *(const bf16x8*)(Wb + (size_t)r * 256 + k0 + s * 8);
    }
    __syncthreads();
    bf16x8 af[4], bfr[4];
    const int rsel = lane & 15, ksl = lane >> 4;
    #pragma unroll
    for (int m = 0; m < 4; ++m) {
      int r = wr + m * 16 + rsel;
      int sw = ksl ^ ((r >> 1) & 3);
      af[m] = *(const bf16x8*)(&As[r * 32 + sw * 8]);
    }
    #pragma unroll
    for (int n = 0; n < 4; ++n) {
      int r = wc + n * 16 + rsel;
      int sw = ksl ^ ((r >> 1) & 3);
      bfr[n] = *(const bf16x8*)(&Bs[r * 32 + sw * 8]);
    }
    #pragma unroll
    for (int m = 0; m < 4; ++m)
      #pragma unroll
      for (int n = 0; n < 4; ++n)
        acc[m][n] = __builtin_amdgcn_mfma_f32_16x16x32_bf16(af[m], bfr[n], acc[m][n], 0, 0, 0);
    __syncthreads();
  }

  const int crow = (lane >> 4) << 2;
  const int ccol = lane & 15;
  #pragma unroll
  for (int m = 0; m < 4; ++m) {
    #pragma unroll
    for (int j = 0; j < 4; ++j) {
      int gr = row0 + wr + m * 16 + crow + j;
      if (gr < NN) {
        #pragma unroll
        for (int n = 0; n < 4; ++n)
          Y[(size_t)gr * 1024 + col0 + wc + n * 16 + ccol] = acc[m][n][j];
      }
    }
  }
}

__device__ __forceinline__ float fast_sigmoid(float z) {
  return __builtin_amdgcn_rcpf(1.0f + __expf(-z));
}
__device__ __forceinline__ float fast_softplus(float z) {
  return fmaxf(z, 0.0f) + __logf(1.0f + __expf(-fabsf(z)));
}

// one wave per dst node: CSR loop, scalar (SGPR) edge metadata, 1-deep gather pipeline
__global__ __launch_bounds__(256) void k_agg(
    const float* __restrict__ Y, const int* __restrict__ roff,
    const int* __restrict__ src_s, const float* __restrict__ rbf_s,
    const float* __restrict__ weff, const float* __restrict__ beff,
    float* __restrict__ xn, __hip_bfloat16* __restrict__ xnb, int layer) {
  __shared__ float WgS[RBFD * EMBD];
  __shared__ float WfS[RBFD * EMBD];
  __shared__ float bS[2 * EMBD];
  const int tid = threadIdx.x;
  const float* wbase = weff + (size_t)layer * 2 * RBFD * EMBD;
  for (int i = tid; i < RBFD * EMBD; i += 256) {
    WgS[i] = wbase[i];
    WfS[i] = wbase[RBFD * EMBD + i];
  }
  for (int i = tid; i < 2 * EMBD; i += 256) bS[i] = beff[(size_t)layer * 2 * EMBD + i];
  __syncthreads();
  const int wave = tid >> 6, lane = tid & 63;
  const int c4 = lane << 2;
  const int n = blockIdx.x * 4 + wave;
  if (n >= NN) return;
  const int deg = roff[n + 1] - roff[n];
  const int jb = __builtin_amdgcn_readfirstlane(roff[n]);

  const float4 bg4 = *(const float4*)&bS[c4];
  const float4 bf4 = *(const float4*)&bS[EMBD + c4];
  const float4 Ax = *(const float4*)(Y + (size_t)n * 1024 + c4);
  const float4 Fx = *(const float4*)(Y + (size_t)n * 1024 + 256 + c4);
  const float bgx = Ax.x + bg4.x, bgy = Ax.y + bg4.y, bgz = Ax.z + bg4.z, bgw = Ax.w + bg4.w;
  const float bfx = Fx.x + bf4.x, bfy = Fx.y + bf4.y, bfz = Fx.z + bf4.z, bfw = Fx.w + bf4.w;

  float4 macc = make_float4(0.f, 0.f, 0.f, 0.f);
  if (deg > 0) {
    const float* Ybase = Y + 512 + c4;
    int scur = src_s[jb];                      // wave-uniform -> s_load
    float4 An = *(const float4*)(Ybase + (size_t)scur * 1024);
    float4 Fn = *(const float4*)(Ybase + 256 + (size_t)scur * 1024);
    for (int i = 0; i < deg; ++i) {
      float4 nAn = An, nFn = Fn;
      if (i + 1 < deg) {
        int sn = src_s[jb + i + 1];            // wave-uniform -> s_load
        nAn = *(const float4*)(Ybase + (size_t)sn * 1024);
        nFn = *(const float4*)(Ybase + 256 + (size_t)sn * 1024);
      }
      const float* rp = rbf_s + (size_t)(jb + i) * RBFD;   // wave-uniform row
      float zgx = bgx + An.x, zgy = bgy + An.y, zgz = bgz + An.z, zgw = bgw + An.w;
      float zfx = bfx + Fn.x, zfy = bfy + Fn.y, zfz = bfz + Fn.z, zfw = bfw + Fn.w;
      #pragma unroll
      for (int k = 0; k < RBFD; ++k) {
        float rk = rp[k];
        const float4 wg = *(const float4*)&WgS[k * EMBD + c4];
        const float4 wf = *(const float4*)&WfS[k * EMBD + c4];
        zgx += rk * wg.x; zgy += rk * wg.y; zgz += rk * wg.z; zgw += rk * wg.w;
        zfx += rk * wf.x; zfy += rk * wf.y; zfz += rk * wf.z; zfw += rk * wf.w;
      }
      macc.x += fast_sigmoid(zgx) * fast_softplus(zfx);
      macc.y += fast_sigmoid(zgy) * fast_softplus(zfy);
      macc.z += fast_sigmoid(zgz) * fast_softplus(zfz);
      macc.w += fast_sigmoid(zgw) * fast_softplus(zfw);
      An = nAn; Fn = nFn;
    }
  }
  float4 xv = *(const float4*)(xn + (size_t)n * EMBD + c4);
  xv.x += macc.x; xv.y += macc.y; xv.z += macc.z; xv.w += macc.w;
  *(float4*)(xn + (size_t)n * EMBD + c4) = xv;
  __hip_bfloat16* xbp = xnb + (size_t)n * EMBD + c4;
  xbp[0] = __float2bfloat16(xv.x); xbp[1] = __float2bfloat16(xv.y);
  xbp[2] = __float2bfloat16(xv.z); xbp[3] = __float2bfloat16(xv.w);
}

// ---------------- readout ----------------

__global__ __launch_bounds__(256) void k_readout(
    const float* __restrict__ xn, const float* __restrict__ Wn,
    const int* __restrict__ gidx, float* __restrict__ gsum, float* __restrict__ gcnt) {
  __shared__ float WnT[12 * EMBD];
  const int tid = threadIdx.x;
  for (int i = tid; i < 12 * EMBD; i += 256) {
    int c = i >> 8, k = i & 255;
    WnT[i] = Wn[k * 12 + c];
  }
  __syncthreads();
  const int wave = tid >> 6, lane = tid & 63;
  const int n = blockIdx.x * 4 + wave;
  if (n >= NN) return;
  float4 xv = *(const float4*)(xn + (size_t)n * EMBD + (lane << 2));
  float acc[12];
  #pragma unroll
  for (int c = 0; c < 12; ++c) {
    const float4 w = *(const float4*)&WnT[c * EMBD + (lane << 2)];
    acc[c] = xv.x * w.x + xv.y * w.y + xv.z * w.z + xv.w * w.w;
  }
  #pragma unroll
  for (int c = 0; c < 12; ++c) {
    float v = acc[c];
    #pragma unroll
    for (int off = 32; off; off >>= 1) v += __shfl_down(v, off, 64);
    acc[c] = v;
  }
  if (lane == 0) {
    int g = gidx[n];
    #pragma unroll
    for (int c = 0; c < 12; ++c) atomicAdd(&gsum[g * 12 + c], acc[c]);
    atomicAdd(&gcnt[g], 1.0f);
  }
}

__global__ void k_final(const float* __restrict__ gsum, const float* __restrict__ gcnt,
                        const float* __restrict__ bn, float* __restrict__ out) {
  int idx = blockIdx.x * blockDim.x + threadIdx.x;
  if (idx >= NG * 12) return;
  int g = idx / 12, c = idx % 12;
  out[idx] = gsum[idx] / fmaxf(gcnt[g], 1.0f) + bn[c];
}

// ---------------- launch ----------------

extern "C" void kernel_launch(void* const* d_in, const int* in_sizes, int n_in,
                              void* d_out, int out_size, void* d_ws, size_t ws_size,
                              hipStream_t stream) {
  const int*   x   = (const int*)d_in[0];
  const int*   src = (const int*)d_in[1];
  const int*   dst = (const int*)d_in[2];
  const float* e   = (const float*)d_in[3];
  const int*   gi  = (const int*)d_in[4];
  const float* emb = (const float*)d_in[5];
  const float* We  = (const float*)d_in[6];
  const float* be  = (const float*)d_in[7];
  const float* Wgx = (const float*)d_in[8];
  const float* Wgn = (const float*)d_in[9];
  const float* Wge = (const float*)d_in[10];
  const float* bg  = (const float*)d_in[11];
  const float* Wfx = (const float*)d_in[12];
  const float* Wfn = (const float*)d_in[13];
  const float* Wfe = (const float*)d_in[14];
  const float* bf  = (const float*)d_in[15];
  const float* Wn  = (const float*)d_in[16];
  const float* bn  = (const float*)d_in[17];
  float* out = (float*)d_out;

  char* ws = (char*)d_ws;
  size_t off = 0;
  auto alloc = [&](size_t bytes) {
    void* p = ws + off;
    off += (bytes + 255) & ~(size_t)255;
    return p;
  };
  float*           xn    = (float*)alloc((size_t)NN * EMBD * 4);
  __hip_bfloat16*  xnb   = (__hip_bfloat16*)alloc((size_t)NN * EMBD * 2);
  float*           Y     = (float*)alloc((size_t)NN * 1024 * 4);
  float*           rbf_s = (float*)alloc((size_t)NE * RBFD * 4);
  int*             src_s = (int*)alloc((size_t)NE * 4);
  int*             cnt   = (int*)alloc((size_t)NN * 4);
  int*             roff  = (int*)alloc((size_t)(NN + 1) * 4);
  int*             curs  = (int*)alloc((size_t)NN * 4);
  float*           weff  = (float*)alloc((size_t)NL * 2 * RBFD * EMBD * 4);
  float*           beff  = (float*)alloc((size_t)NL * 2 * EMBD * 4);
  __hip_bfloat16*  WT    = (__hip_bfloat16*)alloc((size_t)NL * 4 * 256 * 256 * 2);
  float*           gsum  = (float*)alloc((size_t)NG * 12 * 4);
  float*           gcnt  = (float*)alloc((size_t)NG * 4);
  (void)ws_size; (void)in_sizes; (void)n_in; (void)out_size;

  hipMemsetAsync(cnt, 0, (size_t)NN * 4, stream);
  hipMemsetAsync(gsum, 0, (size_t)NG * 12 * 4, stream);
  hipMemsetAsync(gcnt, 0, (size_t)NG * 4, stream);

  k_embed<<<(NN * (EMBD / 4) + 255) / 256, 256, 0, stream>>>(x, emb, xn, xnb);
  k_wsmall<<<(NL * 2 * (RBFD + 1) * EMBD + 255) / 256, 256, 0, stream>>>(
      We, be, Wge, bg, Wfe, bf, weff, beff);
  k_wprep<<<dim3(NL * 4, 16), 256, 0, stream>>>(Wgx, Wfx, Wgn, Wfn, WT);
  k_hist<<<(NE + 255) / 256, 256, 0, stream>>>(dst, cnt);
  k_scan<<<1, 1024, 0, stream>>>(cnt, roff, curs);
  k_scatter<<<(NE + 255) / 256, 256, 0, stream>>>(src, dst, e, curs, src_s, rbf_s);

  dim3 mmgrid((NN + 127) / 128, 8);
  for (int l = 0; l < NL; ++l) {
    k_nodemm<<<mmgrid, 256, 0, stream>>>(xnb, WT + (size_t)l * 4 * 65536, Y);
    k_agg<<<(NN + 3) / 4, 256, 0, stream>>>(Y, roff, src_s, rbf_s, weff, beff, xn, xnb, l);
  }
  k_readout<<<NN / 4, 256, 0, stream>>>(xn, Wn, gi, gsum, gcnt);
  k_final<<<(NG * 12 + 255) / 256, 256, 0, stream>>>(gsum, gcnt, bn, out);
}

// Round 4
// 658.113 us; speedup vs baseline: 5.6966x; 1.1213x over previous
//
#include <hip/hip_runtime.h>
#include <hip/hip_bf16.h>
#include <math.h>

#define NN   20000
#define NE   200000
#define NG   128
#define EMBD 256
#define NL   4
#define RBFD 10

typedef __attribute__((ext_vector_type(8))) short bf16x8;
typedef __attribute__((ext_vector_type(4))) float f32x4;

// ---------------- prep kernels ----------------

__global__ void k_embed(const int* __restrict__ x, const float* __restrict__ emb,
                        float* __restrict__ xn, __hip_bfloat16* __restrict__ xnb) {
  int idx = blockIdx.x * blockDim.x + threadIdx.x;   // float4 index
  if (idx >= NN * (EMBD / 4)) return;
  int n  = idx >> 6;
  int c4 = (idx & 63) << 2;
  float4 v = *(const float4*)(emb + (size_t)x[n] * EMBD + c4);
  *(float4*)(xn + (size_t)n * EMBD + c4) = v;
  __hip_bfloat16* xb = xnb + (size_t)n * EMBD + c4;
  xb[0] = __float2bfloat16(v.x); xb[1] = __float2bfloat16(v.y);
  xb[2] = __float2bfloat16(v.z); xb[3] = __float2bfloat16(v.w);
}

__global__ void k_wsmall(const float* __restrict__ We, const float* __restrict__ be,
                         const float* __restrict__ Wge, const float* __restrict__ bg,
                         const float* __restrict__ Wfe, const float* __restrict__ bf,
                         float* __restrict__ weff, float* __restrict__ beff) {
  int tid = blockIdx.x * blockDim.x + threadIdx.x;
  const int WPER = RBFD * EMBD;   // 2560
  if (tid < NL * 2 * WPER) {
    int l  = tid / (2 * WPER);
    int r  = tid % (2 * WPER);
    int gf = r / WPER;
    int r2 = r % WPER;
    int k = r2 / EMBD, c = r2 % EMBD;
    const float* W = (gf == 0 ? Wge : Wfe) + (size_t)l * EMBD * EMBD;
    float s = 0.f;
    for (int j = 0; j < EMBD; ++j) s += We[k * EMBD + j] * W[(size_t)j * EMBD + c];
    weff[tid] = s;
  } else {
    int t2 = tid - NL * 2 * WPER;
    if (t2 >= NL * 2 * EMBD) return;
    int l  = t2 / (2 * EMBD);
    int r  = t2 % (2 * EMBD);
    int gf = r / EMBD, c = r % EMBD;
    const float* W = (gf == 0 ? Wge : Wfe) + (size_t)l * EMBD * EMBD;
    const float* b = (gf == 0 ? bg : bf) + (size_t)l * EMBD;
    float s = b[c];
    for (int j = 0; j < EMBD; ++j) s += be[j] * W[(size_t)j * EMBD + c];
    beff[t2] = s;
  }
}

// WT[l][q][c][k] = W_q[l][k][c] as bf16 (transposed, K-contiguous)
__global__ __launch_bounds__(256) void k_wprep(
    const float* __restrict__ Wgx, const float* __restrict__ Wfx,
    const float* __restrict__ Wgn, const float* __restrict__ Wfn,
    __hip_bfloat16* __restrict__ WT) {
  __shared__ float T[64][65];
  int lq = blockIdx.x; int l = lq >> 2, q = lq & 3;
  const float* W = (q == 0 ? Wgx : q == 1 ? Wfx : q == 2 ? Wgn : Wfn) + (size_t)l * 65536;
  int t = blockIdx.y;
  int k0 = (t & 3) * 64, c0 = (t >> 2) * 64;
  #pragma unroll
  for (int i = 0; i < 16; ++i) {
    int idx = threadIdx.x + i * 256;
    int r = idx >> 6, c = idx & 63;
    T[r][c] = W[(size_t)(k0 + r) * 256 + c0 + c];
  }
  __syncthreads();
  __hip_bfloat16* out = WT + ((size_t)lq * 256) * 256;
  #pragma unroll
  for (int i = 0; i < 16; ++i) {
    int idx = threadIdx.x + i * 256;
    int r = idx >> 6, c = idx & 63;
    out[(size_t)(c0 + r) * 256 + k0 + c] = __float2bfloat16(T[c][r]);
  }
}

// ---------------- CSR build ----------------

__global__ void k_hist(const int* __restrict__ dst, int* __restrict__ cnt) {
  int e = blockIdx.x * blockDim.x + threadIdx.x;
  if (e >= NE) return;
  atomicAdd(&cnt[dst[e]], 1);
}

__global__ __launch_bounds__(1024) void k_scan(const int* __restrict__ cnt,
                                               int* __restrict__ roff,
                                               int* __restrict__ cursor) {
  __shared__ int part[1024];
  const int t = threadIdx.x;
  const int CH = 20;
  int base = t * CH;
  int loc[CH];
  int s = 0;
  #pragma unroll
  for (int i = 0; i < CH; ++i) {
    int idx = base + i;
    int v = (idx < NN) ? cnt[idx] : 0;
    loc[i] = s;
    s += v;
  }
  part[t] = s;
  __syncthreads();
  for (int off = 1; off < 1024; off <<= 1) {
    int v = (t >= off) ? part[t - off] : 0;
    __syncthreads();
    part[t] += v;
    __syncthreads();
  }
  int chunkbase = (t == 0) ? 0 : part[t - 1];
  #pragma unroll
  for (int i = 0; i < CH; ++i) {
    int idx = base + i;
    if (idx < NN) {
      int v = chunkbase + loc[i];
      roff[idx] = v;
      cursor[idx] = v;
    }
  }
  if (t == 1023) roff[NN] = part[1023];
}

__global__ void k_scatter(const int* __restrict__ src, const int* __restrict__ dst,
                          const float* __restrict__ edist,
                          int* __restrict__ cursor,
                          int* __restrict__ src_s, float* __restrict__ rbf_s) {
  int e = blockIdx.x * blockDim.x + threadIdx.x;
  if (e >= NE) return;
  int d = dst[e];
  int p = atomicAdd(&cursor[d], 1);
  src_s[p] = src[e];
  float dd = edist[e];
  const float width = 8.0f / 9.0f;
  #pragma unroll
  for (int k = 0; k < RBFD; ++k) {
    float t = (dd - (float)k * width) / width;
    rbf_s[(size_t)p * RBFD + k] = __expf(-t * t);
  }
}

// ---------------- per-layer kernels ----------------

// [Y | Yb] = xnb @ [Wg_x | Wf_x || Wg_n | Wf_n]  (bf16 MFMA)
// dst-half (q<2) -> Y f32 (NNx512); src-half (q>=2) -> Yb bf16 (NNx512)
__global__ __launch_bounds__(256) void k_nodemm(
    const __hip_bfloat16* __restrict__ xnb, const __hip_bfloat16* __restrict__ WTl,
    float* __restrict__ Y, __hip_bfloat16* __restrict__ Yb) {
  __shared__ unsigned short As[128 * 32];
  __shared__ unsigned short Bs[128 * 32];
  const int tid = threadIdx.x;
  const int lane = tid & 63;
  const int wave = tid >> 6;
  const int row0 = blockIdx.x << 7;
  const int by = blockIdx.y;
  const int col0 = by << 7;
  const int q = col0 >> 8;
  const int cb = col0 & 255;
  const unsigned short* xb = (const unsigned short*)xnb;
  const unsigned short* Wb = (const unsigned short*)WTl + ((size_t)q * 256 + cb) * 256;
  const int wr = (wave >> 1) << 6;
  const int wc = (wave & 1) << 6;
  f32x4 acc[4][4] = {};

  for (int k0 = 0; k0 < 256; k0 += 32) {
    #pragma unroll
    for (int h = 0; h < 2; ++h) {
      int c = tid + (h << 8);
      int r = c >> 2, s = c & 3;
      int sw = s ^ ((r >> 1) & 3);
      int ga = row0 + r; if (ga > NN - 1) ga = NN - 1;
      *(bf16x8*)(&As[r * 32 + sw * 8]) =
          *(const bf16x8*)(xb + (size_t)ga * 256 + k0 + s * 8);
      *(bf16x8*)(&Bs[r * 32 + sw * 8]) =
          *(const bf16x8*)(Wb + (size_t)r * 256 + k0 + s * 8);
    }
    __syncthreads();
    bf16x8 af[4], bfr[4];
    const int rsel = lane & 15, ksl = lane >> 4;
    #pragma unroll
    for (int m = 0; m < 4; ++m) {
      int r = wr + m * 16 + rsel;
      int sw = ksl ^ ((r >> 1) & 3);
      af[m] = *(const bf16x8*)(&As[r * 32 + sw * 8]);
    }
    #pragma unroll
    for (int n = 0; n < 4; ++n) {
      int r = wc + n * 16 + rsel;
      int sw = ksl ^ ((r >> 1) & 3);
      bfr[n] = *(const bf16x8*)(&Bs[r * 32 + sw * 8]);
    }
    #pragma unroll
    for (int m = 0; m < 4; ++m)
      #pragma unroll
      for (int n = 0; n < 4; ++n)
        acc[m][n] = __builtin_amdgcn_mfma_f32_16x16x32_bf16(af[m], bfr[n], acc[m][n], 0, 0, 0);
    __syncthreads();
  }

  const int crow = (lane >> 4) << 2;
  const int ccol = lane & 15;
  if (by < 4) {
    #pragma unroll
    for (int m = 0; m < 4; ++m)
      #pragma unroll
      for (int j = 0; j < 4; ++j) {
        int gr = row0 + wr + m * 16 + crow + j;
        if (gr < NN) {
          #pragma unroll
          for (int n = 0; n < 4; ++n)
            Y[(size_t)gr * 512 + col0 + wc + n * 16 + ccol] = acc[m][n][j];
        }
      }
  } else {
    const int dcol = col0 - 512;
    #pragma unroll
    for (int m = 0; m < 4; ++m)
      #pragma unroll
      for (int j = 0; j < 4; ++j) {
        int gr = row0 + wr + m * 16 + crow + j;
        if (gr < NN) {
          #pragma unroll
          for (int n = 0; n < 4; ++n)
            Yb[(size_t)gr * 512 + dcol + wc + n * 16 + ccol] = __float2bfloat16(acc[m][n][j]);
        }
      }
  }
}

__device__ __forceinline__ float fast_sigmoid(float z) {
  return __builtin_amdgcn_rcpf(1.0f + __expf(-z));
}
__device__ __forceinline__ float fast_softplus(float z) {
  return fmaxf(z, 0.0f) + __logf(1.0f + __expf(-fabsf(z)));
}

// one wave per dst node: CSR loop, scalar edge metadata, bf16 gathers, 1-deep pipeline
__global__ __launch_bounds__(256) void k_agg(
    const float* __restrict__ Y, const __hip_bfloat16* __restrict__ Yb,
    const int* __restrict__ roff,
    const int* __restrict__ src_s, const float* __restrict__ rbf_s,
    const float* __restrict__ weff, const float* __restrict__ beff,
    float* __restrict__ xn, __hip_bfloat16* __restrict__ xnb, int layer) {
  __shared__ float WgS[RBFD * EMBD];
  __shared__ float WfS[RBFD * EMBD];
  __shared__ float bS[2 * EMBD];
  const int tid = threadIdx.x;
  const float* wbase = weff + (size_t)layer * 2 * RBFD * EMBD;
  for (int i = tid; i < RBFD * EMBD; i += 256) {
    WgS[i] = wbase[i];
    WfS[i] = wbase[RBFD * EMBD + i];
  }
  for (int i = tid; i < 2 * EMBD; i += 256) bS[i] = beff[(size_t)layer * 2 * EMBD + i];
  __syncthreads();
  const int wave = tid >> 6, lane = tid & 63;
  const int c4 = lane << 2;
  const int n = blockIdx.x * 4 + wave;
  if (n >= NN) return;
  const int deg = roff[n + 1] - roff[n];
  const int jb = __builtin_amdgcn_readfirstlane(roff[n]);

  const float4 bg4 = *(const float4*)&bS[c4];
  const float4 bf4 = *(const float4*)&bS[EMBD + c4];
  const float4 Ax = *(const float4*)(Y + (size_t)n * 512 + c4);
  const float4 Fx = *(const float4*)(Y + (size_t)n * 512 + 256 + c4);
  const float bgx = Ax.x + bg4.x, bgy = Ax.y + bg4.y, bgz = Ax.z + bg4.z, bgw = Ax.w + bg4.w;
  const float bfx = Fx.x + bf4.x, bfy = Fx.y + bf4.y, bfz = Fx.z + bf4.z, bfw = Fx.w + bf4.w;

  float4 macc = make_float4(0.f, 0.f, 0.f, 0.f);
  if (deg > 0) {
    const unsigned short* Ybp = (const unsigned short*)Yb + c4;
    int scur = src_s[jb];                      // wave-uniform -> s_load
    uint2 pa = *(const uint2*)(Ybp + (size_t)scur * 512);
    uint2 pf = *(const uint2*)(Ybp + (size_t)scur * 512 + 256);
    for (int i = 0; i < deg; ++i) {
      uint2 na = pa, nf = pf;
      if (i + 1 < deg) {
        int sn = src_s[jb + i + 1];            // wave-uniform -> s_load
        na = *(const uint2*)(Ybp + (size_t)sn * 512);
        nf = *(const uint2*)(Ybp + (size_t)sn * 512 + 256);
      }
      const float* rp = rbf_s + (size_t)(jb + i) * RBFD;   // wave-uniform row
      float zgx = bgx + __uint_as_float(pa.x << 16);
      float zgy = bgy + __uint_as_float(pa.x & 0xffff0000u);
      float zgz = bgz + __uint_as_float(pa.y << 16);
      float zgw = bgw + __uint_as_float(pa.y & 0xffff0000u);
      float zfx = bfx + __uint_as_float(pf.x << 16);
      float zfy = bfy + __uint_as_float(pf.x & 0xffff0000u);
      float zfz = bfz + __uint_as_float(pf.y << 16);
      float zfw = bfw + __uint_as_float(pf.y & 0xffff0000u);
      #pragma unroll
      for (int k = 0; k < RBFD; ++k) {
        float rk = rp[k];
        const float4 wg = *(const float4*)&WgS[k * EMBD + c4];
        const float4 wf = *(const float4*)&WfS[k * EMBD + c4];
        zgx += rk * wg.x; zgy += rk * wg.y; zgz += rk * wg.z; zgw += rk * wg.w;
        zfx += rk * wf.x; zfy += rk * wf.y; zfz += rk * wf.z; zfw += rk * wf.w;
      }
      macc.x += fast_sigmoid(zgx) * fast_softplus(zfx);
      macc.y += fast_sigmoid(zgy) * fast_softplus(zfy);
      macc.z += fast_sigmoid(zgz) * fast_softplus(zfz);
      macc.w += fast_sigmoid(zgw) * fast_softplus(zfw);
      pa = na; pf = nf;
    }
  }
  float4 xv = *(const float4*)(xn + (size_t)n * EMBD + c4);
  xv.x += macc.x; xv.y += macc.y; xv.z += macc.z; xv.w += macc.w;
  *(float4*)(xn + (size_t)n * EMBD + c4) = xv;
  __hip_bfloat16* xbp = xnb + (size_t)n * EMBD + c4;
  xbp[0] = __float2bfloat16(xv.x); xbp[1] = __float2bfloat16(xv.y);
  xbp[2] = __float2bfloat16(xv.z); xbp[3] = __float2bfloat16(xv.w);
}

// ---------------- readout (atomic-free) ----------------

// one block per graph: binary-search node range in sorted gi, sum xn rows
__global__ __launch_bounds__(256) void k_gsum(
    const float* __restrict__ xn, const int* __restrict__ gi,
    float* __restrict__ gsum, float* __restrict__ gcnt) {
  const int g = blockIdx.x;
  int lo = 0, hi = NN;
  while (lo < hi) { int m = (lo + hi) >> 1; if (gi[m] < g) lo = m + 1; else hi = m; }
  int lo2 = lo, hi2 = NN;
  while (lo2 < hi2) { int m = (lo2 + hi2) >> 1; if (gi[m] < g + 1) lo2 = m + 1; else hi2 = m; }
  const int c = threadIdx.x;
  float acc = 0.f;
  for (int r = lo; r < lo2; ++r) acc += xn[(size_t)r * EMBD + c];
  gsum[(size_t)g * EMBD + c] = acc;
  if (c == 0) gcnt[g] = (float)(lo2 - lo);
}

__global__ void k_final(const float* __restrict__ gsum, const float* __restrict__ gcnt,
                        const float* __restrict__ Wn, const float* __restrict__ bn,
                        float* __restrict__ out) {
  int idx = blockIdx.x * blockDim.x + threadIdx.x;
  if (idx >= NG * 12) return;
  int g = idx / 12, c = idx % 12;
  float s = 0.f;
  for (int k = 0; k < EMBD; ++k) s += gsum[(size_t)g * EMBD + k] * Wn[k * 12 + c];
  out[idx] = s / fmaxf(gcnt[g], 1.0f) + bn[c];
}

// ---------------- launch ----------------

extern "C" void kernel_launch(void* const* d_in, const int* in_sizes, int n_in,
                              void* d_out, int out_size, void* d_ws, size_t ws_size,
                              hipStream_t stream) {
  const int*   x   = (const int*)d_in[0];
  const int*   src = (const int*)d_in[1];
  const int*   dst = (const int*)d_in[2];
  const float* e   = (const float*)d_in[3];
  const int*   gi  = (const int*)d_in[4];
  const float* emb = (const float*)d_in[5];
  const float* We  = (const float*)d_in[6];
  const float* be  = (const float*)d_in[7];
  const float* Wgx = (const float*)d_in[8];
  const float* Wgn = (const float*)d_in[9];
  const float* Wge = (const float*)d_in[10];
  const float* bg  = (const float*)d_in[11];
  const float* Wfx = (const float*)d_in[12];
  const float* Wfn = (const float*)d_in[13];
  const float* Wfe = (const float*)d_in[14];
  const float* bf  = (const float*)d_in[15];
  const float* Wn  = (const float*)d_in[16];
  const float* bn  = (const float*)d_in[17];
  float* out = (float*)d_out;

  char* ws = (char*)d_ws;
  size_t off = 0;
  auto alloc = [&](size_t bytes) {
    void* p = ws + off;
    off += (bytes + 255) & ~(size_t)255;
    return p;
  };
  float*           xn    = (float*)alloc((size_t)NN * EMBD * 4);
  __hip_bfloat16*  xnb   = (__hip_bfloat16*)alloc((size_t)NN * EMBD * 2);
  float*           Y     = (float*)alloc((size_t)NN * 512 * 4);
  __hip_bfloat16*  Yb    = (__hip_bfloat16*)alloc((size_t)NN * 512 * 2);
  float*           rbf_s = (float*)alloc((size_t)NE * RBFD * 4);
  int*             src_s = (int*)alloc((size_t)NE * 4);
  int*             cnt   = (int*)alloc((size_t)NN * 4);
  int*             roff  = (int*)alloc((size_t)(NN + 1) * 4);
  int*             curs  = (int*)alloc((size_t)NN * 4);
  float*           weff  = (float*)alloc((size_t)NL * 2 * RBFD * EMBD * 4);
  float*           beff  = (float*)alloc((size_t)NL * 2 * EMBD * 4);
  __hip_bfloat16*  WT    = (__hip_bfloat16*)alloc((size_t)NL * 4 * 256 * 256 * 2);
  float*           gsum  = (float*)alloc((size_t)NG * EMBD * 4);
  float*           gcnt  = (float*)alloc((size_t)NG * 4);
  (void)ws_size; (void)in_sizes; (void)n_in; (void)out_size;

  hipMemsetAsync(cnt, 0, (size_t)NN * 4, stream);

  k_embed<<<(NN * (EMBD / 4) + 255) / 256, 256, 0, stream>>>(x, emb, xn, xnb);
  k_wsmall<<<(NL * 2 * (RBFD + 1) * EMBD + 255) / 256, 256, 0, stream>>>(
      We, be, Wge, bg, Wfe, bf, weff, beff);
  k_wprep<<<dim3(NL * 4, 16), 256, 0, stream>>>(Wgx, Wfx, Wgn, Wfn, WT);
  k_hist<<<(NE + 255) / 256, 256, 0, stream>>>(dst, cnt);
  k_scan<<<1, 1024, 0, stream>>>(cnt, roff, curs);
  k_scatter<<<(NE + 255) / 256, 256, 0, stream>>>(src, dst, e, curs, src_s, rbf_s);

  dim3 mmgrid((NN + 127) / 128, 8);
  for (int l = 0; l < NL; ++l) {
    k_nodemm<<<mmgrid, 256, 0, stream>>>(xnb, WT + (size_t)l * 4 * 65536, Y, Yb);
    k_agg<<<(NN + 3) / 4, 256, 0, stream>>>(Y, Yb, roff, src_s, rbf_s, weff, beff, xn, xnb, l);
  }
  k_gsum<<<NG, 256, 0, stream>>>(xn, gi, gsum, gcnt);
  k_final<<<(NG * 12 + 255) / 256, 256, 0, stream>>>(gsum, gcnt, Wn, bn, out);
}

// Round 5
// 550.377 us; speedup vs baseline: 6.8117x; 1.1957x over previous
//
#include <hip/hip_runtime.h>
#include <hip/hip_bf16.h>
#include <math.h>

#define NN   20000
#define NE   200000
#define NG   128
#define EMBD 256
#define NL   4
#define RBFD 10
#define GSPL 8

typedef __attribute__((ext_vector_type(8))) short bf16x8;
typedef __attribute__((ext_vector_type(4))) float f32x4;
typedef __attribute__((ext_vector_type(2))) float f32x2;

__device__ __forceinline__ f32x2 mk2(float a, float b) { f32x2 r; r.x = a; r.y = b; return r; }
__device__ __forceinline__ f32x2 bfpair(unsigned u) {
  return mk2(__uint_as_float(u << 16), __uint_as_float(u & 0xffff0000u));
}

// ---------------- prep kernels ----------------

__global__ void k_embed(const int* __restrict__ x, const float* __restrict__ emb,
                        float* __restrict__ xn, __hip_bfloat16* __restrict__ xnb) {
  int idx = blockIdx.x * blockDim.x + threadIdx.x;   // float4 index
  if (idx >= NN * (EMBD / 4)) return;
  int n  = idx >> 6;
  int c4 = (idx & 63) << 2;
  float4 v = *(const float4*)(emb + (size_t)x[n] * EMBD + c4);
  *(float4*)(xn + (size_t)n * EMBD + c4) = v;
  __hip_bfloat16* xb = xnb + (size_t)n * EMBD + c4;
  xb[0] = __float2bfloat16(v.x); xb[1] = __float2bfloat16(v.y);
  xb[2] = __float2bfloat16(v.z); xb[3] = __float2bfloat16(v.w);
}

__global__ void k_wsmall(const float* __restrict__ We, const float* __restrict__ be,
                         const float* __restrict__ Wge, const float* __restrict__ bg,
                         const float* __restrict__ Wfe, const float* __restrict__ bf,
                         float* __restrict__ weff, float* __restrict__ beff) {
  int tid = blockIdx.x * blockDim.x + threadIdx.x;
  const int WPER = RBFD * EMBD;   // 2560
  if (tid < NL * 2 * WPER) {
    int l  = tid / (2 * WPER);
    int r  = tid % (2 * WPER);
    int gf = r / WPER;
    int r2 = r % WPER;
    int k = r2 / EMBD, c = r2 % EMBD;
    const float* W = (gf == 0 ? Wge : Wfe) + (size_t)l * EMBD * EMBD;
    float s = 0.f;
    for (int j = 0; j < EMBD; ++j) s += We[k * EMBD + j] * W[(size_t)j * EMBD + c];
    weff[tid] = s;
  } else {
    int t2 = tid - NL * 2 * WPER;
    if (t2 >= NL * 2 * EMBD) return;
    int l  = t2 / (2 * EMBD);
    int r  = t2 % (2 * EMBD);
    int gf = r / EMBD, c = r % EMBD;
    const float* W = (gf == 0 ? Wge : Wfe) + (size_t)l * EMBD * EMBD;
    const float* b = (gf == 0 ? bg : bf) + (size_t)l * EMBD;
    float s = b[c];
    for (int j = 0; j < EMBD; ++j) s += be[j] * W[(size_t)j * EMBD + c];
    beff[t2] = s;
  }
}

// WT[l][q][c][k] = W_q[l][k][c] as bf16 (transposed, K-contiguous)
__global__ __launch_bounds__(256) void k_wprep(
    const float* __restrict__ Wgx, const float* __restrict__ Wfx,
    const float* __restrict__ Wgn, const float* __restrict__ Wfn,
    __hip_bfloat16* __restrict__ WT) {
  __shared__ float T[64][65];
  int lq = blockIdx.x; int l = lq >> 2, q = lq & 3;
  const float* W = (q == 0 ? Wgx : q == 1 ? Wfx : q == 2 ? Wgn : Wfn) + (size_t)l * 65536;
  int t = blockIdx.y;
  int k0 = (t & 3) * 64, c0 = (t >> 2) * 64;
  #pragma unroll
  for (int i = 0; i < 16; ++i) {
    int idx = threadIdx.x + i * 256;
    int r = idx >> 6, c = idx & 63;
    T[r][c] = W[(size_t)(k0 + r) * 256 + c0 + c];
  }
  __syncthreads();
  __hip_bfloat16* out = WT + ((size_t)lq * 256) * 256;
  #pragma unroll
  for (int i = 0; i < 16; ++i) {
    int idx = threadIdx.x + i * 256;
    int r = idx >> 6, c = idx & 63;
    out[(size_t)(c0 + r) * 256 + k0 + c] = __float2bfloat16(T[c][r]);
  }
}

// ---------------- CSR build ----------------

__global__ void k_hist(const int* __restrict__ dst, int* __restrict__ cnt) {
  int e = blockIdx.x * blockDim.x + threadIdx.x;
  if (e >= NE) return;
  atomicAdd(&cnt[dst[e]], 1);
}

__global__ __launch_bounds__(1024) void k_scan(const int* __restrict__ cnt,
                                               int* __restrict__ roff,
                                               int* __restrict__ cursor) {
  __shared__ int part[1024];
  const int t = threadIdx.x;
  const int CH = 20;
  int base = t * CH;
  int loc[CH];
  int s = 0;
  #pragma unroll
  for (int i = 0; i < CH; ++i) {
    int idx = base + i;
    int v = (idx < NN) ? cnt[idx] : 0;
    loc[i] = s;
    s += v;
  }
  part[t] = s;
  __syncthreads();
  for (int off = 1; off < 1024; off <<= 1) {
    int v = (t >= off) ? part[t - off] : 0;
    __syncthreads();
    part[t] += v;
    __syncthreads();
  }
  int chunkbase = (t == 0) ? 0 : part[t - 1];
  #pragma unroll
  for (int i = 0; i < CH; ++i) {
    int idx = base + i;
    if (idx < NN) {
      int v = chunkbase + loc[i];
      roff[idx] = v;
      cursor[idx] = v;
    }
  }
  if (t == 1023) roff[NN] = part[1023];
}

__global__ void k_scatter(const int* __restrict__ src, const int* __restrict__ dst,
                          const float* __restrict__ edist,
                          int* __restrict__ cursor,
                          int* __restrict__ src_s, float* __restrict__ rbf_s) {
  int e = blockIdx.x * blockDim.x + threadIdx.x;
  if (e >= NE) return;
  int d = dst[e];
  int p = atomicAdd(&cursor[d], 1);
  src_s[p] = src[e];
  float dd = edist[e];
  const float width = 8.0f / 9.0f;
  #pragma unroll
  for (int k = 0; k < RBFD; ++k) {
    float t = (dd - (float)k * width) / width;
    rbf_s[(size_t)p * RBFD + k] = __expf(-t * t);
  }
}

// ---------------- per-layer kernels ----------------

// [Y | Yb] = xnb @ [Wg_x | Wf_x || Wg_n | Wf_n]  (bf16 MFMA)
__global__ __launch_bounds__(256) void k_nodemm(
    const __hip_bfloat16* __restrict__ xnb, const __hip_bfloat16* __restrict__ WTl,
    float* __restrict__ Y, __hip_bfloat16* __restrict__ Yb) {
  __shared__ unsigned short As[128 * 32];
  __shared__ unsigned short Bs[128 * 32];
  const int tid = threadIdx.x;
  const int lane = tid & 63;
  const int wave = tid >> 6;
  const int row0 = blockIdx.x << 7;
  const int by = blockIdx.y;
  const int col0 = by << 7;
  const int q = col0 >> 8;
  const int cb = col0 & 255;
  const unsigned short* xb = (const unsigned short*)xnb;
  const unsigned short* Wb = (const unsigned short*)WTl + ((size_t)q * 256 + cb) * 256;
  const int wr = (wave >> 1) << 6;
  const int wc = (wave & 1) << 6;
  f32x4 acc[4][4] = {};

  for (int k0 = 0; k0 < 256; k0 += 32) {
    #pragma unroll
    for (int h = 0; h < 2; ++h) {
      int c = tid + (h << 8);
      int r = c >> 2, s = c & 3;
      int sw = s ^ ((r >> 1) & 3);
      int ga = row0 + r; if (ga > NN - 1) ga = NN - 1;
      *(bf16x8*)(&As[r * 32 + sw * 8]) =
          *(const bf16x8*)(xb + (size_t)ga * 256 + k0 + s * 8);
      *(bf16x8*)(&Bs[r * 32 + sw * 8]) =
          *(const bf16x8*)(Wb + (size_t)r * 256 + k0 + s * 8);
    }
    __syncthreads();
    bf16x8 af[4], bfr[4];
    const int rsel = lane & 15, ksl = lane >> 4;
    #pragma unroll
    for (int m = 0; m < 4; ++m) {
      int r = wr + m * 16 + rsel;
      int sw = ksl ^ ((r >> 1) & 3);
      af[m] = *(const bf16x8*)(&As[r * 32 + sw * 8]);
    }
    #pragma unroll
    for (int n = 0; n < 4; ++n) {
      int r = wc + n * 16 + rsel;
      int sw = ksl ^ ((r >> 1) & 3);
      bfr[n] = *(const bf16x8*)(&Bs[r * 32 + sw * 8]);
    }
    #pragma unroll
    for (int m = 0; m < 4; ++m)
      #pragma unroll
      for (int n = 0; n < 4; ++n)
        acc[m][n] = __builtin_amdgcn_mfma_f32_16x16x32_bf16(af[m], bfr[n], acc[m][n], 0, 0, 0);
    __syncthreads();
  }

  const int crow = (lane >> 4) << 2;
  const int ccol = lane & 15;
  if (by < 4) {
    #pragma unroll
    for (int m = 0; m < 4; ++m)
      #pragma unroll
      for (int j = 0; j < 4; ++j) {
        int gr = row0 + wr + m * 16 + crow + j;
        if (gr < NN) {
          #pragma unroll
          for (int n = 0; n < 4; ++n)
            Y[(size_t)gr * 512 + col0 + wc + n * 16 + ccol] = acc[m][n][j];
        }
      }
  } else {
    const int dcol = col0 - 512;
    #pragma unroll
    for (int m = 0; m < 4; ++m)
      #pragma unroll
      for (int j = 0; j < 4; ++j) {
        int gr = row0 + wr + m * 16 + crow + j;
        if (gr < NN) {
          #pragma unroll
          for (int n = 0; n < 4; ++n)
            Yb[(size_t)gr * 512 + dcol + wc + n * 16 + ccol] = __float2bfloat16(acc[m][n][j]);
        }
      }
  }
}

__device__ __forceinline__ float fast_sigmoid(float z) {
  return __builtin_amdgcn_rcpf(1.0f + __expf(-z));
}
__device__ __forceinline__ float fast_softplus(float z) {
  return fmaxf(z, 0.0f) + __logf(1.0f + __expf(-fabsf(z)));
}

// one wave per dst node: W register-hoisted per node, packed-f32 math,
// scalar edge metadata, 1-deep gather pipeline
__global__ __launch_bounds__(256, 4) void k_agg(
    const float* __restrict__ Y, const __hip_bfloat16* __restrict__ Yb,
    const int* __restrict__ roff,
    const int* __restrict__ src_s, const float* __restrict__ rbf_s,
    const float* __restrict__ weff, const float* __restrict__ beff,
    float* __restrict__ xn, __hip_bfloat16* __restrict__ xnb, int layer) {
  __shared__ float WgS[RBFD * EMBD];
  __shared__ float WfS[RBFD * EMBD];
  __shared__ float bS[2 * EMBD];
  const int tid = threadIdx.x;
  const float* wbase = weff + (size_t)layer * 2 * RBFD * EMBD;
  for (int i = tid; i < RBFD * EMBD; i += 256) {
    WgS[i] = wbase[i];
    WfS[i] = wbase[RBFD * EMBD + i];
  }
  for (int i = tid; i < 2 * EMBD; i += 256) bS[i] = beff[(size_t)layer * 2 * EMBD + i];
  __syncthreads();
  const int wave = tid >> 6, lane = tid & 63;
  const int c4 = lane << 2;
  const int n = blockIdx.x * 4 + wave;
  if (n >= NN) return;
  const int deg = roff[n + 1] - roff[n];
  const int jb = __builtin_amdgcn_readfirstlane(roff[n]);

  // hoist this lane's W slice into registers (constant over the edge loop)
  f32x2 wg0[RBFD], wg1[RBFD], wf0[RBFD], wf1[RBFD];
  #pragma unroll
  for (int k = 0; k < RBFD; ++k) {
    float4 g4 = *(const float4*)&WgS[k * EMBD + c4];
    float4 f4 = *(const float4*)&WfS[k * EMBD + c4];
    wg0[k] = mk2(g4.x, g4.y); wg1[k] = mk2(g4.z, g4.w);
    wf0[k] = mk2(f4.x, f4.y); wf1[k] = mk2(f4.z, f4.w);
  }

  const float4 bg4 = *(const float4*)&bS[c4];
  const float4 bf4 = *(const float4*)&bS[EMBD + c4];
  const float4 Ax = *(const float4*)(Y + (size_t)n * 512 + c4);
  const float4 Fx = *(const float4*)(Y + (size_t)n * 512 + 256 + c4);
  const f32x2 bg0 = mk2(Ax.x + bg4.x, Ax.y + bg4.y);
  const f32x2 bg1 = mk2(Ax.z + bg4.z, Ax.w + bg4.w);
  const f32x2 bf0 = mk2(Fx.x + bf4.x, Fx.y + bf4.y);
  const f32x2 bf1 = mk2(Fx.z + bf4.z, Fx.w + bf4.w);

  f32x2 macc0 = mk2(0.f, 0.f), macc1 = mk2(0.f, 0.f);
  if (deg > 0) {
    const unsigned short* Ybp = (const unsigned short*)Yb + c4;
    int scur = src_s[jb];                      // wave-uniform -> s_load
    uint2 pa = *(const uint2*)(Ybp + (size_t)scur * 512);
    uint2 pf = *(const uint2*)(Ybp + (size_t)scur * 512 + 256);
    for (int i = 0; i < deg; ++i) {
      uint2 na = pa, nf = pf;
      if (i + 1 < deg) {
        int sn = src_s[jb + i + 1];            // wave-uniform -> s_load
        na = *(const uint2*)(Ybp + (size_t)sn * 512);
        nf = *(const uint2*)(Ybp + (size_t)sn * 512 + 256);
      }
      const float* rp = rbf_s + (size_t)(jb + i) * RBFD;   // wave-uniform row
      f32x2 zg0 = bg0 + bfpair(pa.x);
      f32x2 zg1 = bg1 + bfpair(pa.y);
      f32x2 zf0 = bf0 + bfpair(pf.x);
      f32x2 zf1 = bf1 + bfpair(pf.y);
      #pragma unroll
      for (int k = 0; k < RBFD; ++k) {
        float rk = rp[k];
        zg0 += rk * wg0[k]; zg1 += rk * wg1[k];
        zf0 += rk * wf0[k]; zf1 += rk * wf1[k];
      }
      macc0.x += fast_sigmoid(zg0.x) * fast_softplus(zf0.x);
      macc0.y += fast_sigmoid(zg0.y) * fast_softplus(zf0.y);
      macc1.x += fast_sigmoid(zg1.x) * fast_softplus(zf1.x);
      macc1.y += fast_sigmoid(zg1.y) * fast_softplus(zf1.y);
      pa = na; pf = nf;
    }
  }
  float4 xv = *(const float4*)(xn + (size_t)n * EMBD + c4);
  xv.x += macc0.x; xv.y += macc0.y; xv.z += macc1.x; xv.w += macc1.y;
  *(float4*)(xn + (size_t)n * EMBD + c4) = xv;
  __hip_bfloat16* xbp = xnb + (size_t)n * EMBD + c4;
  xbp[0] = __float2bfloat16(xv.x); xbp[1] = __float2bfloat16(xv.y);
  xbp[2] = __float2bfloat16(xv.z); xbp[3] = __float2bfloat16(xv.w);
}

// ---------------- readout (atomic-free, split partials) ----------------

__global__ __launch_bounds__(256) void k_gsum(
    const float* __restrict__ xn, const int* __restrict__ gi,
    float* __restrict__ gpart, float* __restrict__ gcnt) {
  const int g = blockIdx.x, p = blockIdx.y;
  int lo = 0, hi = NN;
  while (lo < hi) { int m = (lo + hi) >> 1; if (gi[m] < g) lo = m + 1; else hi = m; }
  int lo2 = lo, hi2 = NN;
  while (lo2 < hi2) { int m = (lo2 + hi2) >> 1; if (gi[m] < g + 1) lo2 = m + 1; else hi2 = m; }
  const int cntv = lo2 - lo;
  const int r0 = lo + (cntv * p) / GSPL;
  const int r1 = lo + (cntv * (p + 1)) / GSPL;
  const int c = threadIdx.x;
  float acc = 0.f;
  for (int r = r0; r < r1; ++r) acc += xn[(size_t)r * EMBD + c];
  gpart[((size_t)g * GSPL + p) * EMBD + c] = acc;
  if (p == 0 && c == 0) gcnt[g] = (float)cntv;
}

// one block per graph: reduce partials, multiply by Wn
__global__ __launch_bounds__(256) void k_final(
    const float* __restrict__ gpart, const float* __restrict__ gcnt,
    const float* __restrict__ Wn, const float* __restrict__ bn,
    float* __restrict__ out) {
  __shared__ float s[EMBD];
  const int g = blockIdx.x;
  const int c = threadIdx.x;
  float v = 0.f;
  #pragma unroll
  for (int p = 0; p < GSPL; ++p) v += gpart[((size_t)g * GSPL + p) * EMBD + c];
  s[c] = v;
  __syncthreads();
  if (c < 12) {
    float acc = 0.f;
    for (int k = 0; k < EMBD; ++k) acc += s[k] * Wn[k * 12 + c];
    float cv = gcnt[g];
    out[g * 12 + c] = (cv > 0.f) ? acc / cv + bn[c] : 0.f;
  }
}

// ---------------- launch ----------------

extern "C" void kernel_launch(void* const* d_in, const int* in_sizes, int n_in,
                              void* d_out, int out_size, void* d_ws, size_t ws_size,
                              hipStream_t stream) {
  const int*   x   = (const int*)d_in[0];
  const int*   src = (const int*)d_in[1];
  const int*   dst = (const int*)d_in[2];
  const float* e   = (const float*)d_in[3];
  const int*   gi  = (const int*)d_in[4];
  const float* emb = (const float*)d_in[5];
  const float* We  = (const float*)d_in[6];
  const float* be  = (const float*)d_in[7];
  const float* Wgx = (const float*)d_in[8];
  const float* Wgn = (const float*)d_in[9];
  const float* Wge = (const float*)d_in[10];
  const float* bg  = (const float*)d_in[11];
  const float* Wfx = (const float*)d_in[12];
  const float* Wfn = (const float*)d_in[13];
  const float* Wfe = (const float*)d_in[14];
  const float* bf  = (const float*)d_in[15];
  const float* Wn  = (const float*)d_in[16];
  const float* bn  = (const float*)d_in[17];
  float* out = (float*)d_out;

  char* ws = (char*)d_ws;
  size_t off = 0;
  auto alloc = [&](size_t bytes) {
    void* p = ws + off;
    off += (bytes + 255) & ~(size_t)255;
    return p;
  };
  float*           xn    = (float*)alloc((size_t)NN * EMBD * 4);
  __hip_bfloat16*  xnb   = (__hip_bfloat16*)alloc((size_t)NN * EMBD * 2);
  float*           Y     = (float*)alloc((size_t)NN * 512 * 4);
  __hip_bfloat16*  Yb    = (__hip_bfloat16*)alloc((size_t)NN * 512 * 2);
  float*           rbf_s = (float*)alloc((size_t)NE * RBFD * 4);
  int*             src_s = (int*)alloc((size_t)NE * 4);
  int*             cnt   = (int*)alloc((size_t)NN * 4);
  int*             roff  = (int*)alloc((size_t)(NN + 1) * 4);
  int*             curs  = (int*)alloc((size_t)NN * 4);
  float*           weff  = (float*)alloc((size_t)NL * 2 * RBFD * EMBD * 4);
  float*           beff  = (float*)alloc((size_t)NL * 2 * EMBD * 4);
  __hip_bfloat16*  WT    = (__hip_bfloat16*)alloc((size_t)NL * 4 * 256 * 256 * 2);
  float*           gpart = (float*)alloc((size_t)NG * GSPL * EMBD * 4);
  float*           gcnt  = (float*)alloc((size_t)NG * 4);
  (void)ws_size; (void)in_sizes; (void)n_in; (void)out_size;

  hipMemsetAsync(cnt, 0, (size_t)NN * 4, stream);

  k_embed<<<(NN * (EMBD / 4) + 255) / 256, 256, 0, stream>>>(x, emb, xn, xnb);
  k_wsmall<<<(NL * 2 * (RBFD + 1) * EMBD + 255) / 256, 256, 0, stream>>>(
      We, be, Wge, bg, Wfe, bf, weff, beff);
  k_wprep<<<dim3(NL * 4, 16), 256, 0, stream>>>(Wgx, Wfx, Wgn, Wfn, WT);
  k_hist<<<(NE + 255) / 256, 256, 0, stream>>>(dst, cnt);
  k_scan<<<1, 1024, 0, stream>>>(cnt, roff, curs);
  k_scatter<<<(NE + 255) / 256, 256, 0, stream>>>(src, dst, e, curs, src_s, rbf_s);

  dim3 mmgrid((NN + 127) / 128, 8);
  for (int l = 0; l < NL; ++l) {
    k_nodemm<<<mmgrid, 256, 0, stream>>>(xnb, WT + (size_t)l * 4 * 65536, Y, Yb);
    k_agg<<<(NN + 3) / 4, 256, 0, stream>>>(Y, Yb, roff, src_s, rbf_s, weff, beff, xn, xnb, l);
  }
  k_gsum<<<dim3(NG, GSPL), 256, 0, stream>>>(xn, gi, gpart, gcnt);
  k_final<<<NG, 256, 0, stream>>>(gpart, gcnt, Wn, bn, out);
}